// Round 4
// baseline (466.469 us; speedup 1.0000x reference)
//
#include <hip/hip_runtime.h>
#include <math.h>

#define WE 300
#define DEp 256
#define VV 50000
#define DDim 100000
#define BB 4096
#define NGc 10

// panels of 128 columns
#define NP_RV 391   // ceil(50000/128)
#define NP_RD 782   // ceil(100000/128)
#define NENT_RV 40960
#define NENT_RD 45056   // 4096 * 11

__device__ __forceinline__ float wave_reduce(float v) {
    #pragma unroll
    for (int o = 32; o > 0; o >>= 1) v += __shfl_down(v, o, 64);
    return v;
}

// log(sigmoid(x)), numerically stable
__device__ __forceinline__ float logsigf(float x) {
    return (x >= 0.f) ? -log1pf(expf(-x)) : x - log1pf(expf(x));
}

__global__ __launch_bounds__(256) void k_zero(float4* p, int n4) {
    int i = blockIdx.x * blockDim.x + threadIdx.x;
    if (i < n4) p[i] = make_float4(0.f, 0.f, 0.f, 0.f);
}

// Count ids per panel for both matrices; fused sum(proj*proj).
__global__ __launch_bounds__(256) void k_bincount(const int* __restrict__ wid,
                                                  const int* __restrict__ doc,
                                                  const int* __restrict__ neg,
                                                  const float* __restrict__ proj,
                                                  int* __restrict__ cnt_rv,
                                                  int* __restrict__ cnt_rd,
                                                  double* __restrict__ proj_acc) {
    int i = blockIdx.x * blockDim.x + threadIdx.x;   // 0 .. 86015
    float ps = 0.f;
    if (i < WE * DEp) { float v = proj[i]; ps = v * v; }
    if (i < NENT_RV) {
        atomicAdd(&cnt_rv[wid[i] >> 7], 1);
    } else if (i < NENT_RV + NENT_RD) {
        int k = i - NENT_RV;
        int b = k / 11, j = k - b * 11;
        int id = (j == 0) ? doc[b] : neg[b * NGc + j - 1];
        atomicAdd(&cnt_rd[id >> 7], 1);
    }
    float r = wave_reduce(ps);
    __shared__ float part[4];
    int lane = threadIdx.x & 63, wv = threadIdx.x >> 6;
    if (lane == 0) part[wv] = r;
    __syncthreads();
    if (threadIdx.x == 0)
        atomicAdd(proj_acc, (double)(part[0] + part[1] + part[2] + part[3]));
}

// Exclusive scans of both counter arrays (single 1024-thread block).
__global__ __launch_bounds__(1024) void k_scan(const int* __restrict__ cnt_rv,
                                               const int* __restrict__ cnt_rd,
                                               int* __restrict__ offs_rv,
                                               int* __restrict__ offs_rd,
                                               int* __restrict__ cur_rv,
                                               int* __restrict__ cur_rd) {
    __shared__ int s[1024];
    int t = threadIdx.x;
    // --- rv (512 slots used) ---
    int own = (t < 512) ? cnt_rv[t] : 0;
    s[t] = own;
    __syncthreads();
    for (int off = 1; off < 1024; off <<= 1) {
        int v = 0;
        if (t >= off) v = s[t - off];
        __syncthreads();
        s[t] += v;
        __syncthreads();
    }
    if (t < 512) { int e = s[t] - own; offs_rv[t] = e; cur_rv[t] = e; }
    __syncthreads();
    // --- rd (1024 slots) ---
    own = cnt_rd[t];
    s[t] = own;
    __syncthreads();
    for (int off = 1; off < 1024; off <<= 1) {
        int v = 0;
        if (t >= off) v = s[t - off];
        __syncthreads();
        s[t] += v;
        __syncthreads();
    }
    int e = s[t] - own; offs_rd[t] = e; cur_rd[t] = e;
}

// Scatter entries into per-panel lists. entry = (col_local<<16) | payload.
__global__ __launch_bounds__(256) void k_binfill(const int* __restrict__ wid,
                                                 const int* __restrict__ doc,
                                                 const int* __restrict__ neg,
                                                 int* __restrict__ cur_rv,
                                                 int* __restrict__ cur_rd,
                                                 int* __restrict__ ent_rv,
                                                 int* __restrict__ ent_rd) {
    int i = blockIdx.x * blockDim.x + threadIdx.x;
    if (i < NENT_RV) {
        int id = wid[i];
        int b = i / NGc;                       // payload = b
        int pos = atomicAdd(&cur_rv[id >> 7], 1);
        ent_rv[pos] = ((id & 127) << 16) | b;
    } else if (i < NENT_RV + NENT_RD) {
        int k = i - NENT_RV;
        int b = k / 11, j = k - b * 11;
        int id = (j == 0) ? doc[b] : neg[b * NGc + j - 1];
        int pos = atomicAdd(&cur_rd[id >> 7], 1);
        ent_rd[pos] = ((id & 127) << 16) | k;  // payload = b*11+j
    }
}

// Stream rv in (128-col x 64-row) panels; scatter-accumulate into g[b][w].
__global__ __launch_bounds__(256) void k_rvstream(const float* __restrict__ rv,
                                                  const int* __restrict__ offs_rv,
                                                  const int* __restrict__ ent_rv,
                                                  float* __restrict__ g) {
    __shared__ float sd[128 * 65];
    int p = blockIdx.x, q = blockIdx.y;
    int c0 = p * 128, w0 = q * 64;
    int t = threadIdx.x;
    for (int idx = t; idx < 8192; idx += 256) {
        int c = idx & 127, de = idx >> 7;
        int w = w0 + de, col = c0 + c;
        float v = 0.f;
        if (w < WE && col < VV) v = rv[(size_t)w * VV + col];
        sd[c * 65 + de] = v;
    }
    __syncthreads();
    int lo = offs_rv[p], hi = offs_rv[p + 1];
    int lane = t & 63, wv = t >> 6;
    int w = w0 + lane;
    for (int e = lo + wv; e < hi; e += 4) {
        int ent = ent_rv[e];
        int c = ent >> 16, b = ent & 0xFFFF;
        float v = sd[c * 65 + lane];
        if (w < WE) atomicAdd(&g[(size_t)b * WE + w], v);
    }
}

// Normalize g columns (scale-invariant: the /10 mean factor cancels).
__global__ __launch_bounds__(320) void k_norm(const float* __restrict__ g,
                                              float* __restrict__ normed) {
    int b = blockIdx.x;
    int tid = threadIdx.x;
    __shared__ float wpart[5];
    __shared__ float s_inv;
    float gv = 0.f;
    if (tid < WE) gv = g[(size_t)b * WE + tid];
    float r = wave_reduce(gv * gv);
    int lane = tid & 63, wv = tid >> 6;
    if (lane == 0) wpart[wv] = r;
    __syncthreads();
    if (tid == 0) {
        float s = wpart[0] + wpart[1] + wpart[2] + wpart[3] + wpart[4];
        s_inv = 1.0f / sqrtf(s);
    }
    __syncthreads();
    if (tid < WE) normed[(size_t)b * WE + tid] = gv * s_inv;
}

// t_pre[b][de] = sum_w proj[de][w] * normed[b][w].  64x64 tiles, 4x4 micro-tile.
__global__ __launch_bounds__(256) void k_gemm(const float* __restrict__ proj,
                                              const float* __restrict__ normed,
                                              float* __restrict__ tpre) {
    __shared__ float As[64 * 33];
    __shared__ float Bs[64 * 33];
    int tid = threadIdx.x;
    int tx = tid & 15, ty = tid >> 4;
    int de0 = blockIdx.y * 64;
    int b0  = blockIdx.x * 64;
    float acc[4][4] = {};
    int f = tid & 7, r0 = tid >> 3;
    for (int kt = 0; kt < 10; ++kt) {
        int k0 = kt * 32;
        __syncthreads();
        for (int rr = r0; rr < 64; rr += 32) {
            int k = k0 + f * 4;
            float4 va = make_float4(0.f, 0.f, 0.f, 0.f);
            float4 vb = make_float4(0.f, 0.f, 0.f, 0.f);
            if (k + 3 < WE) {
                va = *(const float4*)(proj + (size_t)(de0 + rr) * WE + k);
                vb = *(const float4*)(normed + (size_t)(b0 + rr) * WE + k);
            }
            float* ap = &As[rr * 33 + f * 4];
            ap[0] = va.x; ap[1] = va.y; ap[2] = va.z; ap[3] = va.w;
            float* bp = &Bs[rr * 33 + f * 4];
            bp[0] = vb.x; bp[1] = vb.y; bp[2] = vb.z; bp[3] = vb.w;
        }
        __syncthreads();
        #pragma unroll
        for (int k = 0; k < 32; ++k) {
            float a[4], bv[4];
            #pragma unroll
            for (int i = 0; i < 4; ++i) a[i] = As[(tx * 4 + i) * 33 + k];
            #pragma unroll
            for (int j = 0; j < 4; ++j) bv[j] = Bs[(ty * 4 + j) * 33 + k];
            #pragma unroll
            for (int j = 0; j < 4; ++j)
                #pragma unroll
                for (int i = 0; i < 4; ++i) acc[j][i] += a[i] * bv[j];
        }
    }
    #pragma unroll
    for (int jb = 0; jb < 4; ++jb) {
        int b = b0 + ty * 4 + jb;
        float4 v = make_float4(acc[jb][0], acc[jb][1], acc[jb][2], acc[jb][3]);
        *(float4*)(tpre + (size_t)b * DEp + de0 + tx * 4) = v;
    }
}

__global__ __launch_bounds__(256) void k_stats1(const float* __restrict__ tpre,
                                                double* __restrict__ rowsum,
                                                double* __restrict__ rowsq) {
    int de = threadIdx.x;
    int c0 = blockIdx.x * 64;
    float s = 0.f, ss = 0.f;
    for (int i = 0; i < 64; ++i) {
        float v = tpre[(size_t)(c0 + i) * DEp + de];
        s += v; ss += v * v;
    }
    atomicAdd(&rowsum[de], (double)s);
    atomicAdd(&rowsq[de], (double)ss);
}

__global__ void k_stats2(const double* __restrict__ rowsum, const double* __restrict__ rowsq,
                         float* __restrict__ meanf, float* __restrict__ scalef) {
    int de = threadIdx.x;
    double s = rowsum[de], ss = rowsq[de];
    double mean = s / (double)BB;
    double var = (ss - s * s / (double)BB) / (double)(BB - 1);
    double stdv = sqrt(var);
    meanf[de]  = (float)mean;
    scalef[de] = (float)(1.0 / sqrt(stdv));   // reference divides by sqrt(std) = var^0.25
}

// tpre -> clipped t, in place.
__global__ __launch_bounds__(256) void k_tfin(float* __restrict__ tpre,
                                              const float* __restrict__ meanf,
                                              const float* __restrict__ scalef,
                                              const float* __restrict__ beta) {
    int i = blockIdx.x * blockDim.x + threadIdx.x;   // 0 .. 1048575
    int de = i & 255;
    float v = tpre[i];
    v = (v - meanf[de]) * scalef[de] + beta[de];
    tpre[i] = fminf(1.f, fmaxf(-1.f, v));
}

// Stream rd in (128-col x 64-row) panels; partial dots into x[b*11+j]; fused sum(rd*rd).
__global__ __launch_bounds__(256) void k_rdstream(const float* __restrict__ rd,
                                                  const float* __restrict__ tfin,
                                                  const int* __restrict__ offs_rd,
                                                  const int* __restrict__ ent_rd,
                                                  float* __restrict__ x,
                                                  double* __restrict__ rd_acc) {
    __shared__ float sd[128 * 65];
    int p = blockIdx.x, q = blockIdx.y;
    int c0 = p * 128, de0 = q * 64;
    int t = threadIdx.x;
    float ssq = 0.f;
    for (int idx = t; idx < 8192; idx += 256) {
        int c = idx & 127, de = idx >> 7;
        int col = c0 + c;
        float v = 0.f;
        if (col < DDim) v = rd[(size_t)(de0 + de) * DDim + col];
        sd[c * 65 + de] = v;
        ssq += v * v;
    }
    __syncthreads();
    int lo = offs_rd[p], hi = offs_rd[p + 1];
    int lane = t & 63, wv = t >> 6;
    for (int e = lo + wv; e < hi; e += 4) {
        int ent = ent_rd[e];
        int c = ent >> 16, bj = ent & 0xFFFF;
        int b = bj / 11;
        float tv = tfin[(size_t)b * DEp + de0 + lane];
        float r = wave_reduce(sd[c * 65 + lane] * tv);
        if (lane == 0) atomicAdd(&x[bj], r);
    }
    // fused sum(rd*rd): each element staged exactly once across the grid
    float r = wave_reduce(ssq);
    __shared__ float part[4];
    if (lane == 0) part[wv] = r;
    __syncthreads();
    if (t == 0)
        atomicAdd(rd_acc, (double)(part[0] + part[1] + part[2] + part[3]));
}

// Combine the 11 dots per b into the loss data term.
__global__ __launch_bounds__(256) void k_loss3(const float* __restrict__ x,
                                               double* __restrict__ acc) {
    int b = blockIdx.x * blockDim.x + threadIdx.x;   // 0..4095
    float x0 = x[b * 11];
    float total = 10.f * fminf(logsigf(x0), -1.0005003e-3f);   // Z*log(min(sig,0.999))
    #pragma unroll
    for (int j = 1; j < 11; ++j)
        total += fmaxf(logsigf(-x[b * 11 + j]), -4.6051702f);  // log(max(1-sig,0.01))
    total *= 0.55f;                                            // (Z+1)/(2Z)
    float r = wave_reduce(total);
    int lane = threadIdx.x & 63;
    if (lane == 0) atomicAdd(acc, (double)r);
}

__global__ void k_final(const double* __restrict__ accs, float* __restrict__ out) {
    double loss = accs[0] / (double)BB + (0.01 / (2.0 * (double)BB)) * (accs[1] + accs[2]);
    out[0] = (float)loss;
}

extern "C" void kernel_launch(void* const* d_in, const int* in_sizes, int n_in,
                              void* d_out, int out_size, void* d_ws, size_t ws_size,
                              hipStream_t stream) {
    const float* rv   = (const float*)d_in[0];
    const float* rd   = (const float*)d_in[1];
    const float* proj = (const float*)d_in[2];
    const float* beta = (const float*)d_in[3];
    const int* wid    = (const int*)d_in[4];
    const int* doc    = (const int*)d_in[5];
    const int* neg    = (const int*)d_in[6];
    float* out = (float*)d_out;
    char* ws = (char*)d_ws;

    // ---- workspace layout (need = 14,573,600 B) ----
    float*  g       = (float*)(ws + 0);          // 4,915,200
    float*  x       = (float*)(ws + 4915200);    //   180,224
    int*    cnt_rv  = (int*)  (ws + 5095424);    //     2,048 (512 ints)
    int*    cnt_rd  = (int*)  (ws + 5097472);    //     4,096 (1024 ints)
    double* rowsum  = (double*)(ws + 5101568);   //     2,048
    double* rowsq   = (double*)(ws + 5103616);   //     2,048
    double* accs    = (double*)(ws + 5105664);   //        24  [0]=data [1]=rd [2]=proj
    // --- zero region ends at 5,105,688 (zero 5,105,696 B = 319,106 float4) ---
    int*    offs_rv = (int*)  (ws + 5105696);    //     2,048
    int*    offs_rd = (int*)  (ws + 5107744);    //     4,096
    int*    cur_rv  = (int*)  (ws + 5111840);    //     2,048
    int*    cur_rd  = (int*)  (ws + 5113888);    //     4,096
    int*    ent_rv  = (int*)  (ws + 5117984);    //   163,840
    int*    ent_rd  = (int*)  (ws + 5281824);    //   180,224
    float*  normed  = (float*)(ws + 5462048);    // 4,915,200
    float*  tpre    = (float*)(ws + 10377248);   // 4,194,304
    float*  meanf   = (float*)(ws + 14571552);   //     1,024
    float*  scalef  = (float*)(ws + 14572576);   //     1,024

    k_zero<<<1248, 256, 0, stream>>>((float4*)ws, 319106);
    k_bincount<<<336, 256, 0, stream>>>(wid, doc, neg, proj, cnt_rv, cnt_rd, accs + 2);
    k_scan<<<1, 1024, 0, stream>>>(cnt_rv, cnt_rd, offs_rv, offs_rd, cur_rv, cur_rd);
    k_binfill<<<336, 256, 0, stream>>>(wid, doc, neg, cur_rv, cur_rd, ent_rv, ent_rd);
    k_rvstream<<<dim3(NP_RV, 5), 256, 0, stream>>>(rv, offs_rv, ent_rv, g);
    k_norm<<<BB, 320, 0, stream>>>(g, normed);
    k_gemm<<<dim3(64, 4), 256, 0, stream>>>(proj, normed, tpre);
    k_stats1<<<64, 256, 0, stream>>>(tpre, rowsum, rowsq);
    k_stats2<<<1, 256, 0, stream>>>(rowsum, rowsq, meanf, scalef);
    k_tfin<<<4096, 256, 0, stream>>>(tpre, meanf, scalef, beta);
    k_rdstream<<<dim3(NP_RD, 4), 256, 0, stream>>>(rd, tpre, offs_rd, ent_rd, x, accs + 1);
    k_loss3<<<16, 256, 0, stream>>>(x, accs);
    k_final<<<1, 1, 0, stream>>>(accs, out);
}